// Round 10
// baseline (228.464 us; speedup 1.0000x reference)
//
#include <hip/hip_runtime.h>
#include <stdint.h>

#define INDIM   1024
#define OUTDIM  1024
#define BM 64
#define BN 64
#define BK 64
#define KTILES (INDIM / BK)    // 16
#define PREP_BLOCKS 1024

typedef __attribute__((ext_vector_type(8))) short  short8;   // 8 bf16 (4 VGPRs)
typedef __attribute__((ext_vector_type(4))) float  floatx4;  // MFMA acc

// fp32 pair -> packed bf16x2 (RNE)
__device__ __forceinline__ uint32_t bf16pack(float x, float y) {
    uint32_t ux = __float_as_uint(x);
    ux = ((ux + 0x7FFFu + ((ux >> 16) & 1u)) >> 16) & 0xFFFFu;   // low  = x
    uint32_t uy = __float_as_uint(y);
    uy = (uy + 0x7FFFu + ((uy >> 16) & 1u)) & 0xFFFF0000u;       // high = y
    return ux | uy;
}

// ---------------- fused prep: scatter -> grid barrier -> convert ------------
// R10: replaces scatter + convert dispatches (saves a graph node + gap).
// Grid barrier: 1024 blocks x 256 thr = 4 blocks/CU (co-residency margin:
// waves allow 8), counter zeroed by the same memset that zeros W32T -> no
// dependence on the harness poison value, valid for correctness + timed runs.
__global__ __launch_bounds__(256) void k_prep(
    const int* __restrict__ ind_in, const int* __restrict__ ind_out,
    const float* __restrict__ wgt, int nnz,
    const float4* __restrict__ A32, int nA4,
    float* __restrict__ W32T, uint2* __restrict__ W16T, uint2* __restrict__ A16,
    unsigned* __restrict__ barrier_ctr)
{
    const int gtid = blockIdx.x * 256 + threadIdx.x;   // 0..262143

    // phase 1: scatter into dense W^T (fp32 atomicAdd handles dup (i,o))
    if (gtid < nnz)
        atomicAdd(&W32T[(size_t)ind_out[gtid] * INDIM + ind_in[gtid]], wgt[gtid]);

    // grid barrier (device scope)
    __threadfence();
    __syncthreads();
    if (threadIdx.x == 0) {
        __hip_atomic_fetch_add(barrier_ctr, 1u, __ATOMIC_RELEASE, __HIP_MEMORY_SCOPE_AGENT);
        while (__hip_atomic_load(barrier_ctr, __ATOMIC_ACQUIRE, __HIP_MEMORY_SCOPE_AGENT)
               < (unsigned)PREP_BLOCKS)
            __builtin_amdgcn_s_sleep(4);
    }
    __syncthreads();

    // phase 2a: W fp32 -> bf16. 1M floats = 262144 float4 = exactly one/thread.
    {
        float4 v = ((const float4*)W32T)[gtid];
        W16T[gtid] = make_uint2(bf16pack(v.x, v.y), bf16pack(v.z, v.w));
    }
    // phase 2b: A fp32 -> bf16 (nA4 float4s, 4 per thread at M=4096)
    for (int j = gtid; j < nA4; j += PREP_BLOCKS * 256) {
        float4 v = A32[j];
        A16[j] = make_uint2(bf16pack(v.x, v.y), bf16pack(v.z, v.w));
    }
}

// 16B global -> LDS DMA (gfx950 global_load_lds_dwordx4). LDS dest is
// wave-uniform base + lane*16; our staging layout is linear in t, so base =
// array + (wave index)*512 ushorts.
__device__ __forceinline__ void gload_lds16(const ushort* g, ushort* l) {
    __builtin_amdgcn_global_load_lds(
        (const __attribute__((address_space(1))) void*)g,
        (__attribute__((address_space(3))) void*)l, 16, 0, 0);
}

// ---------------- bf16 MFMA GEMM: C = A16 * W16T^T + bias ------------------
// R10 = R7's proven geometry (64x64x64, 1024 blocks = 4 blocks/CU = 16
// waves/CU; R6/R9 showed 1 block/CU barrier-stalls) with global_load_lds
// staging (m93->m97 lever: no VGPR round-trip, no ds_writes). XOR chunk
// swizzle kept (measured SQ_LDS_BANK_CONFLICT = 0). Verified layouts
// (guide §3): A-frag m=lane&15,k=quad*8+j; B-frag n=lane&15; C/D
// col=lane&15,row=quad*4+r.
__global__ __launch_bounds__(256, 4) void k_gemm(
    const ushort* __restrict__ A16,   // [M][1024] bf16 row-major
    const ushort* __restrict__ W16T,  // [1024 n][1024 k] bf16 row-major
    const float* __restrict__ bias,
    float* __restrict__ C, int M)
{
    __shared__ ushort lA[BM * BK];   // 8 KB
    __shared__ ushort lB[BN * BK];   // 8 KB

    const int t      = threadIdx.x;
    const int w      = t >> 6;
    const int L      = t & 63;
    const int lane15 = L & 15;
    const int lane7  = L & 7;
    const int quad   = L >> 4;
    const int wm     = w >> 1, wn = w & 1;

    // XCD swizzle (bid&7 = XCD round-robin): XCD x owns A rows
    // [x*512, x*512+512) -> per-XCD hot set = 1 MB A16 band + 2 MB W16T.
    const int bid = blockIdx.x;
    const int bm0 = ((bid & 7) * 8 + (bid >> 7)) * BM;
    const int bn0 = ((bid >> 3) & 15) * BN;

    // staging: thread t owns 16B chunks c=t (row t>>3) and c=t+256 (row
    // +32, same row&7). slot = t&7; stored global chunk = slot ^ (row&7).
    const int srow = t >> 3;                       // 0..31
    const int j8   = (t & 7) ^ (srow & 7);

    const ushort* Abase = A16  + (size_t)bm0 * INDIM;
    const ushort* Bbase = W16T + (size_t)bn0 * INDIM;

    // wave-uniform LDS bases for the DMA (thread t -> chunk t = wave base
    // w*512 ushorts + lane*16B; chunk t+256 -> +2048 ushorts)
    ushort* dA0 = lA + w * 512;
    ushort* dA1 = lA + 2048 + w * 512;
    ushort* dB0 = lB + w * 512;
    ushort* dB1 = lB + 2048 + w * 512;

    floatx4 acc[2][2] = {};

    for (int kt = 0; kt < KTILES; ++kt) {
        const int gcol = kt * BK + j8 * 8;
        __syncthreads();                 // previous iter done reading LDS
        gload_lds16(Abase + (size_t)srow        * INDIM + gcol, dA0);
        gload_lds16(Abase + (size_t)(srow + 32) * INDIM + gcol, dA1);
        gload_lds16(Bbase + (size_t)srow        * INDIM + gcol, dB0);
        gload_lds16(Bbase + (size_t)(srow + 32) * INDIM + gcol, dB1);
        __syncthreads();                 // vmcnt drain -> DMA landed

        #pragma unroll
        for (int ks = 0; ks < 2; ++ks) {
            const int koff = (((ks * 4 + quad) ^ lane7) * 8);
            short8 af[2], bf[2];
            #pragma unroll
            for (int tm = 0; tm < 2; ++tm)
                af[tm] = *(const short8*)(lA + (wm * 32 + tm * 16 + lane15) * 64 + koff);
            #pragma unroll
            for (int tn = 0; tn < 2; ++tn)
                bf[tn] = *(const short8*)(lB + (wn * 32 + tn * 16 + lane15) * 64 + koff);
            #pragma unroll
            for (int tm = 0; tm < 2; ++tm)
                #pragma unroll
                for (int tn = 0; tn < 2; ++tn)
                    acc[tm][tn] = __builtin_amdgcn_mfma_f32_16x16x32_bf16(
                        af[tm], bf[tn], acc[tm][tn], 0, 0, 0);
        }
    }

    // ---- epilogue: bias + nontemporal store (C never re-read) ----
    #pragma unroll
    for (int tm = 0; tm < 2; ++tm) {
        #pragma unroll
        for (int tn = 0; tn < 2; ++tn) {
            const int col = bn0 + wn * 32 + tn * 16 + lane15;
            const float bv = bias[col];
            #pragma unroll
            for (int r = 0; r < 4; ++r) {
                const int row = bm0 + wm * 32 + tm * 16 + quad * 4 + r;
                __builtin_nontemporal_store(acc[tm][tn][r] + bv,
                                            &C[(size_t)row * OUTDIM + col]);
            }
        }
    }
}

// ---------------- launcher ----------------
extern "C" void kernel_launch(void* const* d_in, const int* in_sizes, int n_in,
                              void* d_out, int out_size, void* d_ws, size_t ws_size,
                              hipStream_t stream) {
    const float* input  = (const float*)d_in[0];
    const float* weight = (const float*)d_in[1];
    const float* bias   = (const float*)d_in[2];
    const int*   ind_in  = (const int*)d_in[3];
    const int*   ind_out = (const int*)d_in[4];
    float* out = (float*)d_out;

    const int nnz = in_sizes[1];
    const int M   = out_size / OUTDIM;      // 4096
    const int nA4 = M * INDIM / 4;

    char* ws = (char*)d_ws;
    float*    W32T = (float*)ws;                          // 4 MB       @ 0
    unsigned* ctr  = (unsigned*)(ws + (4u << 20));        // 64 B       @ 4 MB
    ushort*   W16T = (ushort*)(ws + (4u << 20) + 4096);   // 2 MB       @ 4 MB + 4 KB
    ushort*   A16  = (ushort*)(ws + (6u << 20) + 4096);   // 8 MB       @ 6 MB + 4 KB

    // one fill zeroes W32T AND the barrier counter
    (void)hipMemsetAsync(ws, 0, (4u << 20) + 4096, stream);
    k_prep<<<PREP_BLOCKS, 256, 0, stream>>>(ind_in, ind_out, weight, nnz,
                                            (const float4*)input, nA4,
                                            W32T, (uint2*)W16T, (uint2*)A16, ctr);
    k_gemm<<<(M / BM) * (OUTDIM / BN), 256, 0, stream>>>(A16, W16T, bias, out, M);
}

// Round 11
// 98.086 us; speedup vs baseline: 2.3292x; 2.3292x over previous
//
#include <hip/hip_runtime.h>
#include <stdint.h>

#define INDIM   1024
#define OUTDIM  1024
#define BM 64
#define BN 64
#define BK 64
#define KTILES (INDIM / BK)    // 16

typedef __attribute__((ext_vector_type(8))) short  short8;   // 8 bf16 (4 VGPRs)
typedef __attribute__((ext_vector_type(4))) float  floatx4;  // MFMA acc

// fp32 pair -> packed bf16x2 (RNE)
__device__ __forceinline__ uint32_t bf16pack(float x, float y) {
    uint32_t ux = __float_as_uint(x);
    ux = ((ux + 0x7FFFu + ((ux >> 16) & 1u)) >> 16) & 0xFFFFu;   // low  = x
    uint32_t uy = __float_as_uint(y);
    uy = (uy + 0x7FFFu + ((uy >> 16) & 1u)) & 0xFFFF0000u;       // high = y
    return ux | uy;
}

// ---- fused scatter + A-convert (independent work, NO grid barrier) --------
// R10 lesson: a software grid barrier on this 8-XCD part costs ~140 us
// (cross-XCD atomic spin + release fences) — never fuse ACROSS a dependency.
// Scatter and A-conversion are independent, so they legally share a dispatch
// and overlap: ~max(3,5) us instead of 3+5 sequential.
__global__ __launch_bounds__(256) void k_prep(
    const int* __restrict__ ind_in, const int* __restrict__ ind_out,
    const float* __restrict__ wgt, int nnz,
    const float4* __restrict__ A32, int nA4,
    float* __restrict__ W32T, uint2* __restrict__ A16)
{
    const int gtid   = blockIdx.x * 256 + threadIdx.x;
    const int stride = gridDim.x * 256;

    if (gtid < nnz)
        atomicAdd(&W32T[(size_t)ind_out[gtid] * INDIM + ind_in[gtid]], wgt[gtid]);

    for (int j = gtid; j < nA4; j += stride) {
        float4 v = A32[j];
        A16[j] = make_uint2(bf16pack(v.x, v.y), bf16pack(v.z, v.w));
    }
}

// ---- W fp32 -> bf16 (depends on scatter; 6 MB traffic, ~1.5 us) -----------
__global__ __launch_bounds__(256) void k_convert_w(
    const float4* __restrict__ Wt, uint2* __restrict__ W16, int n4)
{
    int i = blockIdx.x * 256 + threadIdx.x;
    if (i < n4) {
        float4 v = Wt[i];
        W16[i] = make_uint2(bf16pack(v.x, v.y), bf16pack(v.z, v.w));
    }
}

// 16B global -> LDS DMA (gfx950 global_load_lds_dwordx4). LDS dest is
// wave-uniform base + lane*16; our staging layout is linear in t.
__device__ __forceinline__ void gload_lds16(const ushort* g, ushort* l) {
    __builtin_amdgcn_global_load_lds(
        (const __attribute__((address_space(1))) void*)g,
        (__attribute__((address_space(3))) void*)l, 16, 0, 0);
}

// ---------------- bf16 MFMA GEMM: C = A16 * W16T^T + bias ------------------
// R7's proven geometry (64x64x64, 1024 blocks = 4 blocks/CU = 16 waves/CU;
// R6/R9 showed 1 block/CU barrier-stalls) + global_load_lds staging (m97
// lever; correctness proven in R10 — absmax bit-identical). XOR chunk
// swizzle: measured SQ_LDS_BANK_CONFLICT = 0. Verified layouts (guide §3):
// A-frag m=lane&15,k=quad*8+j; B-frag n=lane&15; C/D col=lane&15,row=quad*4+r.
__global__ __launch_bounds__(256, 4) void k_gemm(
    const ushort* __restrict__ A16,   // [M][1024] bf16 row-major
    const ushort* __restrict__ W16T,  // [1024 n][1024 k] bf16 row-major
    const float* __restrict__ bias,
    float* __restrict__ C, int M)
{
    __shared__ ushort lA[BM * BK];   // 8 KB
    __shared__ ushort lB[BN * BK];   // 8 KB

    const int t      = threadIdx.x;
    const int w      = t >> 6;
    const int L      = t & 63;
    const int lane15 = L & 15;
    const int lane7  = L & 7;
    const int quad   = L >> 4;
    const int wm     = w >> 1, wn = w & 1;

    // XCD swizzle (bid&7 = XCD round-robin): XCD x owns A rows
    // [x*512, x*512+512) -> per-XCD hot set = 1 MB A16 band + 2 MB W16T.
    const int bid = blockIdx.x;
    const int bm0 = ((bid & 7) * 8 + (bid >> 7)) * BM;
    const int bn0 = ((bid >> 3) & 15) * BN;

    // staging: thread t owns 16B chunks c=t (row t>>3) and c=t+256 (row
    // +32, same row&7). slot = t&7; stored global chunk = slot ^ (row&7).
    const int srow = t >> 3;                       // 0..31
    const int j8   = (t & 7) ^ (srow & 7);

    const ushort* Abase = A16  + (size_t)bm0 * INDIM;
    const ushort* Bbase = W16T + (size_t)bn0 * INDIM;

    // wave-uniform LDS bases for the DMA (thread t -> chunk t = wave base
    // w*512 ushorts + lane*16B; chunk t+256 -> +2048 ushorts)
    ushort* dA0 = lA + w * 512;
    ushort* dA1 = lA + 2048 + w * 512;
    ushort* dB0 = lB + w * 512;
    ushort* dB1 = lB + 2048 + w * 512;

    floatx4 acc[2][2] = {};

    for (int kt = 0; kt < KTILES; ++kt) {
        const int gcol = kt * BK + j8 * 8;
        __syncthreads();                 // previous iter done reading LDS
        gload_lds16(Abase + (size_t)srow        * INDIM + gcol, dA0);
        gload_lds16(Abase + (size_t)(srow + 32) * INDIM + gcol, dA1);
        gload_lds16(Bbase + (size_t)srow        * INDIM + gcol, dB0);
        gload_lds16(Bbase + (size_t)(srow + 32) * INDIM + gcol, dB1);
        __syncthreads();                 // vmcnt drain -> DMA landed

        #pragma unroll
        for (int ks = 0; ks < 2; ++ks) {
            const int koff = (((ks * 4 + quad) ^ lane7) * 8);
            short8 af[2], bf[2];
            #pragma unroll
            for (int tm = 0; tm < 2; ++tm)
                af[tm] = *(const short8*)(lA + (wm * 32 + tm * 16 + lane15) * 64 + koff);
            #pragma unroll
            for (int tn = 0; tn < 2; ++tn)
                bf[tn] = *(const short8*)(lB + (wn * 32 + tn * 16 + lane15) * 64 + koff);
            #pragma unroll
            for (int tm = 0; tm < 2; ++tm)
                #pragma unroll
                for (int tn = 0; tn < 2; ++tn)
                    acc[tm][tn] = __builtin_amdgcn_mfma_f32_16x16x32_bf16(
                        af[tm], bf[tn], acc[tm][tn], 0, 0, 0);
        }
    }

    // ---- epilogue: bias + nontemporal store (C never re-read) ----
    #pragma unroll
    for (int tm = 0; tm < 2; ++tm) {
        #pragma unroll
        for (int tn = 0; tn < 2; ++tn) {
            const int col = bn0 + wn * 32 + tn * 16 + lane15;
            const float bv = bias[col];
            #pragma unroll
            for (int r = 0; r < 4; ++r) {
                const int row = bm0 + wm * 32 + tm * 16 + quad * 4 + r;
                __builtin_nontemporal_store(acc[tm][tn][r] + bv,
                                            &C[(size_t)row * OUTDIM + col]);
            }
        }
    }
}

// ---------------- launcher ----------------
extern "C" void kernel_launch(void* const* d_in, const int* in_sizes, int n_in,
                              void* d_out, int out_size, void* d_ws, size_t ws_size,
                              hipStream_t stream) {
    const float* input  = (const float*)d_in[0];
    const float* weight = (const float*)d_in[1];
    const float* bias   = (const float*)d_in[2];
    const int*   ind_in  = (const int*)d_in[3];
    const int*   ind_out = (const int*)d_in[4];
    float* out = (float*)d_out;

    const int nnz = in_sizes[1];
    const int M   = out_size / OUTDIM;      // 4096
    const int nA4 = M * INDIM / 4;          // 1048576

    char* ws = (char*)d_ws;
    float*  W32T = (float*)ws;                    // 4 MB @ 0
    ushort* W16T = (ushort*)(ws + (4u << 20));    // 2 MB @ 4 MB
    ushort* A16  = (ushort*)(ws + (6u << 20));    // 8 MB @ 6 MB

    (void)hipMemsetAsync(W32T, 0, (size_t)OUTDIM * INDIM * sizeof(float), stream);
    k_prep<<<2048, 256, 0, stream>>>(ind_in, ind_out, weight, nnz,
                                     (const float4*)input, nA4, W32T, (uint2*)A16);
    k_convert_w<<<OUTDIM * INDIM / 4 / 256, 256, 0, stream>>>(
        (const float4*)W32T, (uint2*)W16T, OUTDIM * INDIM / 4);
    k_gemm<<<(M / BM) * (OUTDIM / BN), 256, 0, stream>>>(A16, W16T, bias, out, M);
}

// Round 12
// 95.314 us; speedup vs baseline: 2.3970x; 1.0291x over previous
//
#include <hip/hip_runtime.h>
#include <stdint.h>

#define INDIM   1024
#define OUTDIM  1024
#define BM 64
#define BN 64
#define BK 64
#define KTILES (INDIM / BK)    // 16

typedef __attribute__((ext_vector_type(8))) short  short8;   // 8 bf16 (4 VGPRs)
typedef __attribute__((ext_vector_type(4))) float  floatx4;  // MFMA acc

// fp32 pair -> packed bf16x2 (RNE)
__device__ __forceinline__ uint32_t bf16pack(float x, float y) {
    uint32_t ux = __float_as_uint(x);
    ux = ((ux + 0x7FFFu + ((ux >> 16) & 1u)) >> 16) & 0xFFFFu;   // low  = x
    uint32_t uy = __float_as_uint(y);
    uy = (uy + 0x7FFFu + ((uy >> 16) & 1u)) & 0xFFFF0000u;       // high = y
    return ux | uy;
}

// fp32 -> bf16 (RNE) in low 16 bits
__device__ __forceinline__ uint32_t bf16lo(float x) {
    uint32_t u = __float_as_uint(x);
    return ((u + 0x7FFFu + ((u >> 16) & 1u)) >> 16) & 0xFFFFu;
}

// CDNA4 packed bf16 atomic add (gfx940+): mem.bf16x2 += data.bf16x2.
// Inline asm (no builtin-name roulette); addr = 64b VGPR pair, data = v32.
__device__ __forceinline__ void atomic_pk_add_bf16(uint32_t* addr, uint32_t val) {
    asm volatile("global_atomic_pk_add_bf16 %0, %1, off"
                 :: "v"(addr), "v"(val) : "memory");
}

// ---- fused scatter + A-convert (independent work, NO grid barrier) --------
// R10 lesson: software grid barrier costs ~140 us on this 8-XCD part; only
// fuse independent work. R12: scatter goes DIRECTLY to bf16 W16T via
// global_atomic_pk_add_bf16 (other lane +0.0 = exact no-op; ~1300 duplicate
// (i,o) pairs get one extra bf16 rounding, negligible) -> kills k_convert_w,
// W32T, and one graph gap; memset shrinks 4 MB -> 2 MB.
__global__ __launch_bounds__(256) void k_prep(
    const int* __restrict__ ind_in, const int* __restrict__ ind_out,
    const float* __restrict__ wgt, int nnz,
    const float4* __restrict__ A32, int nA4,
    uint32_t* __restrict__ W16T, uint2* __restrict__ A16)
{
    const int gtid   = blockIdx.x * 256 + threadIdx.x;
    const int stride = gridDim.x * 256;

    if (gtid < nnz) {
        const uint32_t idx = ((uint32_t)ind_out[gtid] << 10) | (uint32_t)ind_in[gtid];
        const uint32_t w16 = bf16lo(wgt[gtid]);
        atomic_pk_add_bf16(W16T + (idx >> 1), (idx & 1) ? (w16 << 16) : w16);
    }

    for (int j = gtid; j < nA4; j += stride) {
        float4 v = A32[j];
        A16[j] = make_uint2(bf16pack(v.x, v.y), bf16pack(v.z, v.w));
    }
}

// 16B global -> LDS DMA (gfx950 global_load_lds_dwordx4). LDS dest is
// wave-uniform base + lane*16; our staging layout is linear in t.
__device__ __forceinline__ void gload_lds16(const ushort* g, ushort* l) {
    __builtin_amdgcn_global_load_lds(
        (const __attribute__((address_space(1))) void*)g,
        (__attribute__((address_space(3))) void*)l, 16, 0, 0);
}

// ---------------- bf16 MFMA GEMM: C = A16 * W16T^T + bias ------------------
// Byte-identical to R11's 98.1 us winner: 64x64x64, 1024 blocks = 4
// blocks/CU = 16 waves/CU (R6/R9: 1 block/CU barrier-stalls), DMA staging
// (m97 lever, proven R10/R11), XOR chunk swizzle (SQ_LDS_BANK_CONFLICT = 0).
// Verified layouts (guide §3): A-frag m=lane&15,k=quad*8+j; B-frag n=lane&15;
// C/D col=lane&15,row=quad*4+r.
__global__ __launch_bounds__(256, 4) void k_gemm(
    const ushort* __restrict__ A16,   // [M][1024] bf16 row-major
    const ushort* __restrict__ W16T,  // [1024 n][1024 k] bf16 row-major
    const float* __restrict__ bias,
    float* __restrict__ C, int M)
{
    __shared__ ushort lA[BM * BK];   // 8 KB
    __shared__ ushort lB[BN * BK];   // 8 KB

    const int t      = threadIdx.x;
    const int w      = t >> 6;
    const int L      = t & 63;
    const int lane15 = L & 15;
    const int lane7  = L & 7;
    const int quad   = L >> 4;
    const int wm     = w >> 1, wn = w & 1;

    // XCD swizzle (bid&7 = XCD round-robin): XCD x owns A rows
    // [x*512, x*512+512) -> per-XCD hot set = 1 MB A16 band + 2 MB W16T.
    const int bid = blockIdx.x;
    const int bm0 = ((bid & 7) * 8 + (bid >> 7)) * BM;
    const int bn0 = ((bid >> 3) & 15) * BN;

    // staging: thread t owns 16B chunks c=t (row t>>3) and c=t+256 (row
    // +32, same row&7). slot = t&7; stored global chunk = slot ^ (row&7).
    const int srow = t >> 3;                       // 0..31
    const int j8   = (t & 7) ^ (srow & 7);

    const ushort* Abase = A16  + (size_t)bm0 * INDIM;
    const ushort* Bbase = W16T + (size_t)bn0 * INDIM;

    // wave-uniform LDS bases for the DMA (thread t -> chunk t = wave base
    // w*512 ushorts + lane*16B; chunk t+256 -> +2048 ushorts)
    ushort* dA0 = lA + w * 512;
    ushort* dA1 = lA + 2048 + w * 512;
    ushort* dB0 = lB + w * 512;
    ushort* dB1 = lB + 2048 + w * 512;

    floatx4 acc[2][2] = {};

    for (int kt = 0; kt < KTILES; ++kt) {
        const int gcol = kt * BK + j8 * 8;
        __syncthreads();                 // previous iter done reading LDS
        gload_lds16(Abase + (size_t)srow        * INDIM + gcol, dA0);
        gload_lds16(Abase + (size_t)(srow + 32) * INDIM + gcol, dA1);
        gload_lds16(Bbase + (size_t)srow        * INDIM + gcol, dB0);
        gload_lds16(Bbase + (size_t)(srow + 32) * INDIM + gcol, dB1);
        __syncthreads();                 // vmcnt drain -> DMA landed

        #pragma unroll
        for (int ks = 0; ks < 2; ++ks) {
            const int koff = (((ks * 4 + quad) ^ lane7) * 8);
            short8 af[2], bf[2];
            #pragma unroll
            for (int tm = 0; tm < 2; ++tm)
                af[tm] = *(const short8*)(lA + (wm * 32 + tm * 16 + lane15) * 64 + koff);
            #pragma unroll
            for (int tn = 0; tn < 2; ++tn)
                bf[tn] = *(const short8*)(lB + (wn * 32 + tn * 16 + lane15) * 64 + koff);
            #pragma unroll
            for (int tm = 0; tm < 2; ++tm)
                #pragma unroll
                for (int tn = 0; tn < 2; ++tn)
                    acc[tm][tn] = __builtin_amdgcn_mfma_f32_16x16x32_bf16(
                        af[tm], bf[tn], acc[tm][tn], 0, 0, 0);
        }
    }

    // ---- epilogue: bias + nontemporal store (C never re-read) ----
    #pragma unroll
    for (int tm = 0; tm < 2; ++tm) {
        #pragma unroll
        for (int tn = 0; tn < 2; ++tn) {
            const int col = bn0 + wn * 32 + tn * 16 + lane15;
            const float bv = bias[col];
            #pragma unroll
            for (int r = 0; r < 4; ++r) {
                const int row = bm0 + wm * 32 + tm * 16 + quad * 4 + r;
                __builtin_nontemporal_store(acc[tm][tn][r] + bv,
                                            &C[(size_t)row * OUTDIM + col]);
            }
        }
    }
}

// ---------------- launcher ----------------
extern "C" void kernel_launch(void* const* d_in, const int* in_sizes, int n_in,
                              void* d_out, int out_size, void* d_ws, size_t ws_size,
                              hipStream_t stream) {
    const float* input  = (const float*)d_in[0];
    const float* weight = (const float*)d_in[1];
    const float* bias   = (const float*)d_in[2];
    const int*   ind_in  = (const int*)d_in[3];
    const int*   ind_out = (const int*)d_in[4];
    float* out = (float*)d_out;

    const int nnz = in_sizes[1];
    const int M   = out_size / OUTDIM;      // 4096
    const int nA4 = M * INDIM / 4;          // 1048576

    char* ws = (char*)d_ws;
    ushort* W16T = (ushort*)ws;                   // 2 MB @ 0
    ushort* A16  = (ushort*)(ws + (2u << 20));    // 8 MB @ 2 MB

    (void)hipMemsetAsync(W16T, 0, (size_t)OUTDIM * INDIM * sizeof(ushort), stream);
    k_prep<<<2048, 256, 0, stream>>>(ind_in, ind_out, weight, nnz,
                                     (const float4*)input, nA4,
                                     (uint32_t*)W16T, (uint2*)A16);
    k_gemm<<<(M / BM) * (OUTDIM / BN), 256, 0, stream>>>(A16, W16T, bias, out, M);
}